// Round 9
// baseline (823.420 us; speedup 1.0000x reference)
//
#include <hip/hip_runtime.h>

static constexpr int NN  = 100000;   // nodes
static constexpr int NE  = 1200000;  // edges
static constexpr int KIN = 256;      // input dim
static constexpr int HID = 64;       // hidden == output dim

// ---------- zero helper (avoid hipMemsetAsync during graph capture)
__global__ void k_zero(int* __restrict__ p, int n) {
  int i = blockIdx.x * 256 + threadIdx.x;
  if (i < n) p[i] = 0;
}

// ---------- degree histogram (in-degree from edges only; +1 self-loop in dinv)
__global__ void k_deg(const int* __restrict__ ed, int* __restrict__ edeg) {
  int e = blockIdx.x * 256 + threadIdx.x;
  if (e < NE) atomicAdd(&edeg[ed[NE + e]], 1);
}

__global__ void k_dinv(const int* __restrict__ edeg, float* __restrict__ dinv) {
  int i = blockIdx.x * 256 + threadIdx.x;
  if (i < NN) dinv[i] = rsqrtf((float)(edeg[i] + 1));
}

// ---------- exclusive scan of edeg -> row_ptr (1024 elems/block -> nb = 98 blocks)
__global__ void k_scan1(const int* __restrict__ deg, int* __restrict__ rp, int* __restrict__ bsum) {
  __shared__ int sh[256];
  int t = threadIdx.x;
  int base = blockIdx.x * 1024 + t * 4;
  int v0 = 0, v1 = 0, v2 = 0, v3 = 0;
  if (base + 0 < NN) v0 = deg[base + 0];
  if (base + 1 < NN) v1 = deg[base + 1];
  if (base + 2 < NN) v2 = deg[base + 2];
  if (base + 3 < NN) v3 = deg[base + 3];
  int s = v0 + v1 + v2 + v3;
  sh[t] = s;
  __syncthreads();
  #pragma unroll
  for (int off = 1; off < 256; off <<= 1) {
    int x = (t >= off) ? sh[t - off] : 0;
    __syncthreads();
    sh[t] += x;
    __syncthreads();
  }
  int pre = sh[t] - s;
  if (t == 255) bsum[blockIdx.x] = sh[255];
  if (base + 0 < NN) rp[base + 0] = pre;
  pre += v0;
  if (base + 1 < NN) rp[base + 1] = pre;
  pre += v1;
  if (base + 2 < NN) rp[base + 2] = pre;
  pre += v2;
  if (base + 3 < NN) rp[base + 3] = pre;
}

// parallel 128-lane scan of block sums (nb <= 128) — replaces serial 1-thread loop
__global__ void k_scan2(int* __restrict__ bsum, int nb) {
  __shared__ int sh[128];
  int t = threadIdx.x;
  int v = (t < nb) ? bsum[t] : 0;
  sh[t] = v;
  __syncthreads();
  #pragma unroll
  for (int off = 1; off < 128; off <<= 1) {
    int x = (t >= off) ? sh[t - off] : 0;
    __syncthreads();
    sh[t] += x;
    __syncthreads();
  }
  if (t < nb) bsum[t] = sh[t] - v;  // exclusive
}

__global__ void k_scan3(int* __restrict__ rp, const int* __restrict__ bsum, int* __restrict__ cur) {
  int i = blockIdx.x * 256 + threadIdx.x;
  if (i < NN) {
    int v = rp[i] + bsum[i >> 10];
    rp[i] = v;
    cur[i] = v;
  }
}

__global__ void k_scatter(const int* __restrict__ ed, int* __restrict__ cur, int* __restrict__ csr) {
  int e = blockIdx.x * 256 + threadIdx.x;
  if (e < NE) {
    int src = ed[e];
    int dst = ed[NE + e];
    int pos = atomicAdd(&cur[dst], 1);
    csr[pos] = src;
  }
}

// ---------- GEMM: Y[r][c] = sum_k X[r][k] * W[c][k]  (torch Linear layout W[out][in])
// Block = 64 rows x 4 waves (256 thr). lane = row (1 row/thread, 16 acc), wave = 16-col slab.
// BOTH operands from LDS:
//   - X tile [64][KT=32], row stride 36 floats (144B = 16B mod 128B -> b128 conflict-free)
//   - W tile [64][32] packed; reads wave-uniform -> LDS broadcast (free), no s_load in loop.
// 17.4 KB LDS + <=64 VGPR -> 8 blocks/CU; grid = 1563 blocks -> real occupancy.
// MODE 0: Y = dinv[r]*acc; MODE 1: Y = relu(acc + bias).
template<int K, int MODE>
__global__ void __launch_bounds__(256, 8)
k_gemm(const float* __restrict__ X, const float* __restrict__ W,
       const float* __restrict__ dinv, const float* __restrict__ bias,
       float* __restrict__ Y) {
  constexpr int KT = 32;
  constexpr int NT = K / KT;
  constexpr int LS = 36;                 // X row stride in floats
  __shared__ float xl[64 * LS];          // 9216 B
  __shared__ float wl[64 * KT];          // 8192 B

  const int t = threadIdx.x;
  const int lane = t & 63;
  const int wc = (t >> 6) * 16;          // wave's column base
  const int rowbase = blockIdx.x * 64;
  const int grow = rowbase + lane;

  float acc[16];
  #pragma unroll
  for (int c = 0; c < 16; ++c) acc[c] = 0.f;

  const int sr = t >> 3;                 // staging: 32 rows/pass (8 thr/row)
  const int sc = (t & 7) * 4;

  for (int kt = 0; kt < NT; ++kt) {
    __syncthreads();                     // everyone done reading previous tile
    // stage X tile: 64 rows x 32 floats (512 float4; 2 per thread), coalesced
    #pragma unroll
    for (int p = 0; p < 2; ++p) {
      int r = p * 32 + sr;
      int gr = rowbase + r;
      float4 v = make_float4(0.f, 0.f, 0.f, 0.f);
      if (gr < NN) v = *reinterpret_cast<const float4*>(X + (size_t)gr * K + kt * KT + sc);
      *reinterpret_cast<float4*>(&xl[r * LS + sc]) = v;
    }
    // stage W tile: 64 cols x 32 floats (512 float4; 2 per thread), coalesced
    #pragma unroll
    for (int q = 0; q < 2; ++q) {
      int idx = q * 256 + t;
      int c = idx >> 3;
      int slot = (idx & 7) * 4;
      *reinterpret_cast<float4*>(&wl[c * KT + slot]) =
          *reinterpret_cast<const float4*>(W + (size_t)c * K + kt * KT + slot);
    }
    __syncthreads();

    #pragma unroll
    for (int k0 = 0; k0 < 8; ++k0) {
      float4 xv = *reinterpret_cast<const float4*>(&xl[lane * LS + k0 * 4]);
      #pragma unroll
      for (int c = 0; c < 16; ++c) {
        float4 wv = *reinterpret_cast<const float4*>(&wl[(wc + c) * KT + k0 * 4]);
        acc[c] = fmaf(xv.x, wv.x, fmaf(xv.y, wv.y,
                 fmaf(xv.z, wv.z, fmaf(xv.w, wv.w, acc[c]))));
      }
    }
  }

  if (grow < NN) {
    float dv = (MODE == 0) ? dinv[grow] : 0.f;
    #pragma unroll
    for (int c4 = 0; c4 < 4; ++c4) {
      float4 o;
      o.x = acc[c4 * 4 + 0]; o.y = acc[c4 * 4 + 1];
      o.z = acc[c4 * 4 + 2]; o.w = acc[c4 * 4 + 3];
      if (MODE == 0) {
        o.x *= dv; o.y *= dv; o.z *= dv; o.w *= dv;
      } else {
        o.x = fmaxf(o.x + bias[wc + c4 * 4 + 0], 0.f);
        o.y = fmaxf(o.y + bias[wc + c4 * 4 + 1], 0.f);
        o.z = fmaxf(o.z + bias[wc + c4 * 4 + 2], 0.f);
        o.w = fmaxf(o.w + bias[wc + c4 * 4 + 3], 0.f);
      }
      *reinterpret_cast<float4*>(Y + (size_t)grow * HID + wc + c4 * 4) = o;
    }
  }
}

// ---------- aggregation over pre-scaled rows T' (= dinv.*T). One wave per node, lane = feature.
// Fixed 16-wide predicated gather: 16 independent loads in flight per wave.
// MODE 0 (layer1): O = dinv[node] * relu(dinv[node]*sum + bias[lane])   (outputs h')
// MODE 1 (layer2): O = dinv[node] * sum                                 (outputs g)
template<int MODE>
__global__ void __launch_bounds__(256, 8)
k_agg(const float* __restrict__ T, const int* __restrict__ csr,
      const int* __restrict__ rp, const int* __restrict__ edeg,
      const float* __restrict__ dinv, const float* __restrict__ bias,
      float* __restrict__ O) {
  int node = blockIdx.x * 4 + (threadIdx.x >> 6);
  int lane = threadIdx.x & 63;
  float acc = T[(size_t)node * HID + lane];   // self-loop term (pre-scaled)
  int start = rp[node];
  int len = edeg[node];
  for (int base = 0; base < len; base += 64) {
    int m = min(64, len - base);
    int idx = (lane < m) ? csr[start + base + lane] : 0;   // coalesced index load
    for (int c0 = 0; c0 < m; c0 += 16) {
      float part = 0.f;
      #pragma unroll
      for (int i = 0; i < 16; ++i) {
        int e = c0 + i;
        int s = __shfl(idx, e & 63);
        float v = T[(size_t)s * HID + lane];   // always issued; 16 in flight
        part += (e < m) ? v : 0.f;
      }
      acc += part;
    }
  }
  float dv = dinv[node];
  if (MODE == 0) acc = dv * fmaxf(fmaf(dv, acc, bias[lane]), 0.f);
  else           acc = dv * acc;
  O[(size_t)node * HID + lane] = acc;
}

extern "C" void kernel_launch(void* const* d_in, const int* in_sizes, int n_in,
                              void* d_out, int out_size, void* d_ws, size_t ws_size,
                              hipStream_t stream) {
  const float* x  = (const float*)d_in[0];
  const int*   ed = (const int*)d_in[1];   // int32 per harness contract
  const float* W1 = (const float*)d_in[2];
  const float* b1 = (const float*)d_in[3];
  const float* W2 = (const float*)d_in[4];
  const float* b2 = (const float*)d_in[5];
  float* out = (float*)d_out;

  char* ws = (char*)d_ws;
  size_t off = 0;
  auto alloc = [&](size_t bytes) {
    char* p = ws + off;
    off = (off + bytes + 255) & ~(size_t)255;
    return p;
  };
  int*   edeg = (int*)alloc((size_t)NN * 4);
  float* dinv = (float*)alloc((size_t)NN * 4);
  int*   rp   = (int*)alloc((size_t)NN * 4);
  int*   cur  = (int*)alloc((size_t)NN * 4);
  int*   bsum = (int*)alloc(4096);
  int*   csr  = (int*)alloc((size_t)NE * 4);
  float* A    = (float*)alloc((size_t)NN * HID * 4);  // t1' then g; d_out doubles as h'

  // ---- CSR build
  k_zero<<<(NN + 255) / 256, 256, 0, stream>>>(edeg, NN);
  k_deg<<<(NE + 255) / 256, 256, 0, stream>>>(ed, edeg);
  k_dinv<<<(NN + 255) / 256, 256, 0, stream>>>(edeg, dinv);
  int nb = (NN + 1023) / 1024;   // 98
  k_scan1<<<nb, 256, 0, stream>>>(edeg, rp, bsum);
  k_scan2<<<1, 128, 0, stream>>>(bsum, nb);
  k_scan3<<<(NN + 255) / 256, 256, 0, stream>>>(rp, bsum, cur);
  k_scatter<<<(NE + 255) / 256, 256, 0, stream>>>(ed, cur, csr);

  const int GB = (NN + 63) / 64;  // 1563 gemm blocks (64 rows each)

  // layer 1: A = dinv .* (x @ W1^T) ; out(h') = dinv .* relu(dinv.*(Agg A) + b1)
  k_gemm<KIN, 0><<<GB, 256, 0, stream>>>(x, W1, dinv, b1, A);
  k_agg<0><<<NN / 4, 256, 0, stream>>>(A, csr, rp, edeg, dinv, b1, out);

  // layer 2 (agg commutes with right-linear): A(g) = dinv .* (Agg h') ; out = relu(g @ W2^T + b2)
  k_agg<1><<<NN / 4, 256, 0, stream>>>(out, csr, rp, edeg, dinv, b2, A);
  k_gemm<HID, 1><<<GB, 256, 0, stream>>>(A, W2, dinv, b2, out);
}

// Round 10
// 367.465 us; speedup vs baseline: 2.2408x; 2.2408x over previous
//
#include <hip/hip_runtime.h>

static constexpr int NN  = 100000;   // nodes
static constexpr int NE  = 1200000;  // edges
static constexpr int KIN = 256;      // input dim
static constexpr int HID = 64;       // hidden == output dim

// ---------- zero helper (avoid hipMemsetAsync during graph capture)
__global__ void k_zero(int* __restrict__ p, int n) {
  int i = blockIdx.x * 256 + threadIdx.x;
  if (i < n) p[i] = 0;
}

// ---------- degree histogram (in-degree from edges only; +1 self-loop in dinv)
__global__ void k_deg(const int* __restrict__ ed, int* __restrict__ edeg) {
  int e = blockIdx.x * 256 + threadIdx.x;
  if (e < NE) atomicAdd(&edeg[ed[NE + e]], 1);
}

__global__ void k_dinv(const int* __restrict__ edeg, float* __restrict__ dinv) {
  int i = blockIdx.x * 256 + threadIdx.x;
  if (i < NN) dinv[i] = rsqrtf((float)(edeg[i] + 1));
}

// ---------- exclusive scan of edeg -> row_ptr (1024 elems/block -> nb = 98 blocks)
__global__ void k_scan1(const int* __restrict__ deg, int* __restrict__ rp, int* __restrict__ bsum) {
  __shared__ int sh[256];
  int t = threadIdx.x;
  int base = blockIdx.x * 1024 + t * 4;
  int v0 = 0, v1 = 0, v2 = 0, v3 = 0;
  if (base + 0 < NN) v0 = deg[base + 0];
  if (base + 1 < NN) v1 = deg[base + 1];
  if (base + 2 < NN) v2 = deg[base + 2];
  if (base + 3 < NN) v3 = deg[base + 3];
  int s = v0 + v1 + v2 + v3;
  sh[t] = s;
  __syncthreads();
  #pragma unroll
  for (int off = 1; off < 256; off <<= 1) {
    int x = (t >= off) ? sh[t - off] : 0;
    __syncthreads();
    sh[t] += x;
    __syncthreads();
  }
  int pre = sh[t] - s;
  if (t == 255) bsum[blockIdx.x] = sh[255];
  if (base + 0 < NN) rp[base + 0] = pre;
  pre += v0;
  if (base + 1 < NN) rp[base + 1] = pre;
  pre += v1;
  if (base + 2 < NN) rp[base + 2] = pre;
  pre += v2;
  if (base + 3 < NN) rp[base + 3] = pre;
}

// parallel 128-lane scan of block sums (nb <= 128) — replaces serial 1-thread loop
__global__ void k_scan2(int* __restrict__ bsum, int nb) {
  __shared__ int sh[128];
  int t = threadIdx.x;
  int v = (t < nb) ? bsum[t] : 0;
  sh[t] = v;
  __syncthreads();
  #pragma unroll
  for (int off = 1; off < 128; off <<= 1) {
    int x = (t >= off) ? sh[t - off] : 0;
    __syncthreads();
    sh[t] += x;
    __syncthreads();
  }
  if (t < nb) bsum[t] = sh[t] - v;  // exclusive
}

__global__ void k_scan3(int* __restrict__ rp, const int* __restrict__ bsum, int* __restrict__ cur) {
  int i = blockIdx.x * 256 + threadIdx.x;
  if (i < NN) {
    int v = rp[i] + bsum[i >> 10];
    rp[i] = v;
    cur[i] = v;
  }
}

__global__ void k_scatter(const int* __restrict__ ed, int* __restrict__ cur, int* __restrict__ csr) {
  int e = blockIdx.x * 256 + threadIdx.x;
  if (e < NE) {
    int src = ed[e];
    int dst = ed[NE + e];
    int pos = atomicAdd(&cur[dst], 1);
    csr[pos] = src;
  }
}

// ---------- GEMM: Y[r][c] = sum_k X[r][k] * W[c][k]  (torch Linear layout W[out][in])
// Block = 64 rows x 4 waves (256 thr). lane = row (1 row/thread, 16 acc), wave = 16-col slab.
// BOTH operands from LDS:
//   - X tile [64][KT=32], row stride 36 floats (144B = 16B mod 128B -> b128 conflict-free)
//   - W tile [64][32] packed; reads wave-uniform -> LDS broadcast (free), no s_load in loop.
// __launch_bounds__(256,4): 128-VGPR budget. Loop needs ~50 (acc16 + xv4 + wv4 + addr +
// staging) — (256,8)'s 64-cap made the allocator squeeze to 32 and SPILL (round 9:
// WRITE_SIZE 1.1 GB of scratch, 5x slowdown). Registers first, occupancy second.
// MODE 0: Y = dinv[r]*acc; MODE 1: Y = relu(acc + bias).
template<int K, int MODE>
__global__ void __launch_bounds__(256, 4)
k_gemm(const float* __restrict__ X, const float* __restrict__ W,
       const float* __restrict__ dinv, const float* __restrict__ bias,
       float* __restrict__ Y) {
  constexpr int KT = 32;
  constexpr int NT = K / KT;
  constexpr int LS = 36;                 // X row stride in floats
  __shared__ float xl[64 * LS];          // 9216 B
  __shared__ float wl[64 * KT];          // 8192 B

  const int t = threadIdx.x;
  const int lane = t & 63;
  const int wc = (t >> 6) * 16;          // wave's column base
  const int rowbase = blockIdx.x * 64;
  const int grow = rowbase + lane;

  float acc[16];
  #pragma unroll
  for (int c = 0; c < 16; ++c) acc[c] = 0.f;

  const int sr = t >> 3;                 // staging: 32 rows/pass (8 thr/row)
  const int sc = (t & 7) * 4;

  for (int kt = 0; kt < NT; ++kt) {
    __syncthreads();                     // everyone done reading previous tile
    // stage X tile: 64 rows x 32 floats (512 float4; 2 per thread), coalesced
    #pragma unroll
    for (int p = 0; p < 2; ++p) {
      int r = p * 32 + sr;
      int gr = rowbase + r;
      float4 v = make_float4(0.f, 0.f, 0.f, 0.f);
      if (gr < NN) v = *reinterpret_cast<const float4*>(X + (size_t)gr * K + kt * KT + sc);
      *reinterpret_cast<float4*>(&xl[r * LS + sc]) = v;
    }
    // stage W tile: 64 cols x 32 floats (512 float4; 2 per thread), coalesced
    #pragma unroll
    for (int q = 0; q < 2; ++q) {
      int idx = q * 256 + t;
      int c = idx >> 3;
      int slot = (idx & 7) * 4;
      *reinterpret_cast<float4*>(&wl[c * KT + slot]) =
          *reinterpret_cast<const float4*>(W + (size_t)c * K + kt * KT + slot);
    }
    __syncthreads();

    #pragma unroll
    for (int k0 = 0; k0 < 8; ++k0) {
      float4 xv = *reinterpret_cast<const float4*>(&xl[lane * LS + k0 * 4]);
      #pragma unroll
      for (int c = 0; c < 16; ++c) {
        float4 wv = *reinterpret_cast<const float4*>(&wl[(wc + c) * KT + k0 * 4]);
        acc[c] = fmaf(xv.x, wv.x, fmaf(xv.y, wv.y,
                 fmaf(xv.z, wv.z, fmaf(xv.w, wv.w, acc[c]))));
      }
    }
  }

  if (grow < NN) {
    float dv = (MODE == 0) ? dinv[grow] : 0.f;
    #pragma unroll
    for (int c4 = 0; c4 < 4; ++c4) {
      float4 o;
      o.x = acc[c4 * 4 + 0]; o.y = acc[c4 * 4 + 1];
      o.z = acc[c4 * 4 + 2]; o.w = acc[c4 * 4 + 3];
      if (MODE == 0) {
        o.x *= dv; o.y *= dv; o.z *= dv; o.w *= dv;
      } else {
        o.x = fmaxf(o.x + bias[wc + c4 * 4 + 0], 0.f);
        o.y = fmaxf(o.y + bias[wc + c4 * 4 + 1], 0.f);
        o.z = fmaxf(o.z + bias[wc + c4 * 4 + 2], 0.f);
        o.w = fmaxf(o.w + bias[wc + c4 * 4 + 3], 0.f);
      }
      *reinterpret_cast<float4*>(Y + (size_t)grow * HID + wc + c4 * 4) = o;
    }
  }
}

// ---------- aggregation over pre-scaled rows T' (= dinv.*T). One wave per node, lane = feature.
// Fixed 16-wide predicated gather: 16 independent loads in flight per wave.
// MODE 0 (layer1): O = dinv[node] * relu(dinv[node]*sum + bias[lane])   (outputs h')
// MODE 1 (layer2): O = dinv[node] * sum                                 (outputs g)
template<int MODE>
__global__ void __launch_bounds__(256, 8)
k_agg(const float* __restrict__ T, const int* __restrict__ csr,
      const int* __restrict__ rp, const int* __restrict__ edeg,
      const float* __restrict__ dinv, const float* __restrict__ bias,
      float* __restrict__ O) {
  int node = blockIdx.x * 4 + (threadIdx.x >> 6);
  int lane = threadIdx.x & 63;
  float acc = T[(size_t)node * HID + lane];   // self-loop term (pre-scaled)
  int start = rp[node];
  int len = edeg[node];
  for (int base = 0; base < len; base += 64) {
    int m = min(64, len - base);
    int idx = (lane < m) ? csr[start + base + lane] : 0;   // coalesced index load
    for (int c0 = 0; c0 < m; c0 += 16) {
      float part = 0.f;
      #pragma unroll
      for (int i = 0; i < 16; ++i) {
        int e = c0 + i;
        int s = __shfl(idx, e & 63);
        float v = T[(size_t)s * HID + lane];   // always issued; 16 in flight
        part += (e < m) ? v : 0.f;
      }
      acc += part;
    }
  }
  float dv = dinv[node];
  if (MODE == 0) acc = dv * fmaxf(fmaf(dv, acc, bias[lane]), 0.f);
  else           acc = dv * acc;
  O[(size_t)node * HID + lane] = acc;
}

extern "C" void kernel_launch(void* const* d_in, const int* in_sizes, int n_in,
                              void* d_out, int out_size, void* d_ws, size_t ws_size,
                              hipStream_t stream) {
  const float* x  = (const float*)d_in[0];
  const int*   ed = (const int*)d_in[1];   // int32 per harness contract
  const float* W1 = (const float*)d_in[2];
  const float* b1 = (const float*)d_in[3];
  const float* W2 = (const float*)d_in[4];
  const float* b2 = (const float*)d_in[5];
  float* out = (float*)d_out;

  char* ws = (char*)d_ws;
  size_t off = 0;
  auto alloc = [&](size_t bytes) {
    char* p = ws + off;
    off = (off + bytes + 255) & ~(size_t)255;
    return p;
  };
  int*   edeg = (int*)alloc((size_t)NN * 4);
  float* dinv = (float*)alloc((size_t)NN * 4);
  int*   rp   = (int*)alloc((size_t)NN * 4);
  int*   cur  = (int*)alloc((size_t)NN * 4);
  int*   bsum = (int*)alloc(4096);
  int*   csr  = (int*)alloc((size_t)NE * 4);
  float* A    = (float*)alloc((size_t)NN * HID * 4);  // t1' then g; d_out doubles as h'

  // ---- CSR build
  k_zero<<<(NN + 255) / 256, 256, 0, stream>>>(edeg, NN);
  k_deg<<<(NE + 255) / 256, 256, 0, stream>>>(ed, edeg);
  k_dinv<<<(NN + 255) / 256, 256, 0, stream>>>(edeg, dinv);
  int nb = (NN + 1023) / 1024;   // 98
  k_scan1<<<nb, 256, 0, stream>>>(edeg, rp, bsum);
  k_scan2<<<1, 128, 0, stream>>>(bsum, nb);
  k_scan3<<<(NN + 255) / 256, 256, 0, stream>>>(rp, bsum, cur);
  k_scatter<<<(NE + 255) / 256, 256, 0, stream>>>(ed, cur, csr);

  const int GB = (NN + 63) / 64;  // 1563 gemm blocks (64 rows each)

  // layer 1: A = dinv .* (x @ W1^T) ; out(h') = dinv .* relu(dinv.*(Agg A) + b1)
  k_gemm<KIN, 0><<<GB, 256, 0, stream>>>(x, W1, dinv, b1, A);
  k_agg<0><<<NN / 4, 256, 0, stream>>>(A, csr, rp, edeg, dinv, b1, out);

  // layer 2 (agg commutes with right-linear): A(g) = dinv .* (Agg h') ; out = relu(g @ W2^T + b2)
  k_agg<1><<<NN / 4, 256, 0, stream>>>(out, csr, rp, edeg, dinv, b2, A);
  k_gemm<HID, 1><<<GB, 256, 0, stream>>>(A, W2, dinv, b2, out);
}

// Round 11
// 340.342 us; speedup vs baseline: 2.4194x; 1.0797x over previous
//
#include <hip/hip_runtime.h>

static constexpr int NN  = 100000;   // nodes
static constexpr int NE  = 1200000;  // edges
static constexpr int KIN = 256;      // input dim
static constexpr int HID = 64;       // hidden == output dim

// ---------- bf16 helpers (exact widen; RNE narrow)
__device__ __forceinline__ float bf2f(unsigned short u) {
  return __uint_as_float(((unsigned int)u) << 16);
}
__device__ __forceinline__ unsigned short f2bf(float f) {
  unsigned int b = __float_as_uint(f);
  return (unsigned short)((b + 0x7FFFu + ((b >> 16) & 1u)) >> 16);
}

// ---------- zero helper (avoid hipMemsetAsync during graph capture)
__global__ void k_zero(int* __restrict__ p, int n) {
  int i = blockIdx.x * 256 + threadIdx.x;
  if (i < n) p[i] = 0;
}

// ---------- degree histogram (in-degree from edges only; +1 self-loop in dinv)
__global__ void k_deg(const int* __restrict__ ed, int* __restrict__ edeg) {
  int e = blockIdx.x * 256 + threadIdx.x;
  if (e < NE) atomicAdd(&edeg[ed[NE + e]], 1);
}

__global__ void k_dinv(const int* __restrict__ edeg, float* __restrict__ dinv) {
  int i = blockIdx.x * 256 + threadIdx.x;
  if (i < NN) dinv[i] = rsqrtf((float)(edeg[i] + 1));
}

// ---------- exclusive scan of edeg -> row_ptr (1024 elems/block -> nb = 98 blocks)
__global__ void k_scan1(const int* __restrict__ deg, int* __restrict__ rp, int* __restrict__ bsum) {
  __shared__ int sh[256];
  int t = threadIdx.x;
  int base = blockIdx.x * 1024 + t * 4;
  int v0 = 0, v1 = 0, v2 = 0, v3 = 0;
  if (base + 0 < NN) v0 = deg[base + 0];
  if (base + 1 < NN) v1 = deg[base + 1];
  if (base + 2 < NN) v2 = deg[base + 2];
  if (base + 3 < NN) v3 = deg[base + 3];
  int s = v0 + v1 + v2 + v3;
  sh[t] = s;
  __syncthreads();
  #pragma unroll
  for (int off = 1; off < 256; off <<= 1) {
    int x = (t >= off) ? sh[t - off] : 0;
    __syncthreads();
    sh[t] += x;
    __syncthreads();
  }
  int pre = sh[t] - s;
  if (t == 255) bsum[blockIdx.x] = sh[255];
  if (base + 0 < NN) rp[base + 0] = pre;
  pre += v0;
  if (base + 1 < NN) rp[base + 1] = pre;
  pre += v1;
  if (base + 2 < NN) rp[base + 2] = pre;
  pre += v2;
  if (base + 3 < NN) rp[base + 3] = pre;
}

// parallel 128-lane scan of block sums (nb <= 128)
__global__ void k_scan2(int* __restrict__ bsum, int nb) {
  __shared__ int sh[128];
  int t = threadIdx.x;
  int v = (t < nb) ? bsum[t] : 0;
  sh[t] = v;
  __syncthreads();
  #pragma unroll
  for (int off = 1; off < 128; off <<= 1) {
    int x = (t >= off) ? sh[t - off] : 0;
    __syncthreads();
    sh[t] += x;
    __syncthreads();
  }
  if (t < nb) bsum[t] = sh[t] - v;  // exclusive
}

__global__ void k_scan3(int* __restrict__ rp, const int* __restrict__ bsum, int* __restrict__ cur) {
  int i = blockIdx.x * 256 + threadIdx.x;
  if (i < NN) {
    int v = rp[i] + bsum[i >> 10];
    rp[i] = v;
    cur[i] = v;
  }
}

__global__ void k_scatter(const int* __restrict__ ed, int* __restrict__ cur, int* __restrict__ csr) {
  int e = blockIdx.x * 256 + threadIdx.x;
  if (e < NE) {
    int src = ed[e];
    int dst = ed[NE + e];
    int pos = atomicAdd(&cur[dst], 1);
    csr[pos] = src;
  }
}

// ---------- GEMM: Y[r][c] = sum_k X[r][k] * W[c][k]  (torch Linear layout W[out][in])
// Block = 128 rows x 4 waves. Thread owns rows {lane, lane+64} (rr=2) and 16 cols [wc,wc+16).
// Both operands from LDS: X tile [128][32] (row stride 36 floats, measured 0-conflict),
// W tile [64][32] (wave-uniform broadcast reads, measured 0-conflict).
// rr=2 halves ds_read:FMA ratio (18:128 vs 17:64) -> fewer lgkmcnt stalls per FMA.
// __launch_bounds__(256,4): 128-VGPR budget (needs ~70; (256,8) caused a 1.1 GB spill storm).
// MODE 0: Y(bf16) = dinv[r]*acc; MODE 1: Y(fp32) = relu(acc + bias).
template<int K, int MODE>
__global__ void __launch_bounds__(256, 4)
k_gemm(const float* __restrict__ X, const float* __restrict__ W,
       const float* __restrict__ dinv, const float* __restrict__ bias,
       void* __restrict__ Yv) {
  constexpr int KT = 32;
  constexpr int NT = K / KT;
  constexpr int LS = 36;                 // X row stride in floats
  __shared__ float xl[128 * LS];         // 18432 B
  __shared__ float wl[64 * KT];          // 8192 B

  const int t = threadIdx.x;
  const int lane = t & 63;
  const int wc = (t >> 6) * 16;          // wave's column base
  const int rowbase = blockIdx.x * 128;

  float acc[2][16];
  #pragma unroll
  for (int rr = 0; rr < 2; ++rr)
    #pragma unroll
    for (int c = 0; c < 16; ++c) acc[rr][c] = 0.f;

  const int sr = t >> 3;                 // staging: 32 rows/pass (8 thr/row)
  const int sc = (t & 7) * 4;

  for (int kt = 0; kt < NT; ++kt) {
    __syncthreads();                     // everyone done reading previous tile
    // stage X tile: 128 rows x 32 floats (1024 float4; 4 per thread), coalesced
    #pragma unroll
    for (int p = 0; p < 4; ++p) {
      int r = p * 32 + sr;
      int gr = rowbase + r;
      float4 v = make_float4(0.f, 0.f, 0.f, 0.f);
      if (gr < NN) v = *reinterpret_cast<const float4*>(X + (size_t)gr * K + kt * KT + sc);
      *reinterpret_cast<float4*>(&xl[r * LS + sc]) = v;
    }
    // stage W tile: 64 cols x 32 floats (512 float4; 2 per thread), coalesced
    #pragma unroll
    for (int q = 0; q < 2; ++q) {
      int idx = q * 256 + t;
      int c = idx >> 3;
      int slot = (idx & 7) * 4;
      *reinterpret_cast<float4*>(&wl[c * KT + slot]) =
          *reinterpret_cast<const float4*>(W + (size_t)c * K + kt * KT + slot);
    }
    __syncthreads();

    #pragma unroll
    for (int k0 = 0; k0 < 8; ++k0) {
      float4 xv0 = *reinterpret_cast<const float4*>(&xl[lane * LS + k0 * 4]);
      float4 xv1 = *reinterpret_cast<const float4*>(&xl[(64 + lane) * LS + k0 * 4]);
      #pragma unroll
      for (int c = 0; c < 16; ++c) {
        float4 wv = *reinterpret_cast<const float4*>(&wl[(wc + c) * KT + k0 * 4]);
        acc[0][c] = fmaf(xv0.x, wv.x, fmaf(xv0.y, wv.y,
                    fmaf(xv0.z, wv.z, fmaf(xv0.w, wv.w, acc[0][c]))));
        acc[1][c] = fmaf(xv1.x, wv.x, fmaf(xv1.y, wv.y,
                    fmaf(xv1.z, wv.z, fmaf(xv1.w, wv.w, acc[1][c]))));
      }
    }
  }

  #pragma unroll
  for (int rr = 0; rr < 2; ++rr) {
    int grow = rowbase + rr * 64 + lane;
    if (grow < NN) {
      if (MODE == 0) {
        // bf16 output, pre-scaled by dinv[r]
        float dv = dinv[grow];
        unsigned short* yh = (unsigned short*)Yv + (size_t)grow * HID + wc;
        uint4 o0, o1;
        o0.x = (unsigned)f2bf(acc[rr][0] * dv)  | ((unsigned)f2bf(acc[rr][1] * dv) << 16);
        o0.y = (unsigned)f2bf(acc[rr][2] * dv)  | ((unsigned)f2bf(acc[rr][3] * dv) << 16);
        o0.z = (unsigned)f2bf(acc[rr][4] * dv)  | ((unsigned)f2bf(acc[rr][5] * dv) << 16);
        o0.w = (unsigned)f2bf(acc[rr][6] * dv)  | ((unsigned)f2bf(acc[rr][7] * dv) << 16);
        o1.x = (unsigned)f2bf(acc[rr][8] * dv)  | ((unsigned)f2bf(acc[rr][9] * dv) << 16);
        o1.y = (unsigned)f2bf(acc[rr][10] * dv) | ((unsigned)f2bf(acc[rr][11] * dv) << 16);
        o1.z = (unsigned)f2bf(acc[rr][12] * dv) | ((unsigned)f2bf(acc[rr][13] * dv) << 16);
        o1.w = (unsigned)f2bf(acc[rr][14] * dv) | ((unsigned)f2bf(acc[rr][15] * dv) << 16);
        *reinterpret_cast<uint4*>(yh)     = o0;
        *reinterpret_cast<uint4*>(yh + 8) = o1;
      } else {
        float* yf = (float*)Yv + (size_t)grow * HID + wc;
        #pragma unroll
        for (int c4 = 0; c4 < 4; ++c4) {
          float4 o;
          o.x = fmaxf(acc[rr][c4 * 4 + 0] + bias[wc + c4 * 4 + 0], 0.f);
          o.y = fmaxf(acc[rr][c4 * 4 + 1] + bias[wc + c4 * 4 + 1], 0.f);
          o.z = fmaxf(acc[rr][c4 * 4 + 2] + bias[wc + c4 * 4 + 2], 0.f);
          o.w = fmaxf(acc[rr][c4 * 4 + 3] + bias[wc + c4 * 4 + 3], 0.f);
          *reinterpret_cast<float4*>(yf + c4 * 4) = o;
        }
      }
    }
  }
}

// ---------- aggregation over pre-scaled bf16 rows T' (= dinv.*T). One wave per node,
// lane = feature. Fixed 16-wide predicated gather (16 loads in flight). fp32 accumulate.
// MODE 0 (layer1): O(bf16) = dinv[node] * relu(dinv[node]*sum + bias[lane])   (h')
// MODE 1 (layer2): O(fp32) = dinv[node] * sum                                 (g)
template<int MODE>
__global__ void __launch_bounds__(256, 8)
k_agg(const unsigned short* __restrict__ T, const int* __restrict__ csr,
      const int* __restrict__ rp, const int* __restrict__ edeg,
      const float* __restrict__ dinv, const float* __restrict__ bias,
      void* __restrict__ Ov) {
  int node = blockIdx.x * 4 + (threadIdx.x >> 6);
  int lane = threadIdx.x & 63;
  float acc = bf2f(T[(size_t)node * HID + lane]);   // self-loop term (pre-scaled)
  int start = rp[node];
  int len = edeg[node];
  for (int base = 0; base < len; base += 64) {
    int m = min(64, len - base);
    int idx = (lane < m) ? csr[start + base + lane] : 0;   // coalesced index load
    for (int c0 = 0; c0 < m; c0 += 16) {
      float part = 0.f;
      #pragma unroll
      for (int i = 0; i < 16; ++i) {
        int e = c0 + i;
        int s = __shfl(idx, e & 63);
        float v = bf2f(T[(size_t)s * HID + lane]);   // always issued; 16 in flight
        part += (e < m) ? v : 0.f;
      }
      acc += part;
    }
  }
  float dv = dinv[node];
  if (MODE == 0) {
    float h = dv * fmaxf(fmaf(dv, acc, bias[lane]), 0.f);
    ((unsigned short*)Ov)[(size_t)node * HID + lane] = f2bf(h);
  } else {
    ((float*)Ov)[(size_t)node * HID + lane] = dv * acc;
  }
}

extern "C" void kernel_launch(void* const* d_in, const int* in_sizes, int n_in,
                              void* d_out, int out_size, void* d_ws, size_t ws_size,
                              hipStream_t stream) {
  const float* x  = (const float*)d_in[0];
  const int*   ed = (const int*)d_in[1];   // int32 per harness contract
  const float* W1 = (const float*)d_in[2];
  const float* b1 = (const float*)d_in[3];
  const float* W2 = (const float*)d_in[4];
  const float* b2 = (const float*)d_in[5];
  float* out = (float*)d_out;

  char* ws = (char*)d_ws;
  size_t off = 0;
  auto alloc = [&](size_t bytes) {
    char* p = ws + off;
    off = (off + bytes + 255) & ~(size_t)255;
    return p;
  };
  int*   edeg = (int*)alloc((size_t)NN * 4);
  float* dinv = (float*)alloc((size_t)NN * 4);
  int*   rp   = (int*)alloc((size_t)NN * 4);
  int*   cur  = (int*)alloc((size_t)NN * 4);
  int*   bsum = (int*)alloc(4096);
  int*   csr  = (int*)alloc((size_t)NE * 4);
  // A: first used as bf16 t1' table (12.8 MB), later overwritten as fp32 g (25.6 MB)
  float* A    = (float*)alloc((size_t)NN * HID * 4);
  // h' (bf16, 12.8 MB) lives in d_out's first half; final GEMM overwrites all of d_out.
  unsigned short* Hp = (unsigned short*)d_out;

  // ---- CSR build
  k_zero<<<(NN + 255) / 256, 256, 0, stream>>>(edeg, NN);
  k_deg<<<(NE + 255) / 256, 256, 0, stream>>>(ed, edeg);
  k_dinv<<<(NN + 255) / 256, 256, 0, stream>>>(edeg, dinv);
  int nb = (NN + 1023) / 1024;   // 98
  k_scan1<<<nb, 256, 0, stream>>>(edeg, rp, bsum);
  k_scan2<<<1, 128, 0, stream>>>(bsum, nb);
  k_scan3<<<(NN + 255) / 256, 256, 0, stream>>>(rp, bsum, cur);
  k_scatter<<<(NE + 255) / 256, 256, 0, stream>>>(ed, cur, csr);

  const int GB = (NN + 127) / 128;  // 782 gemm blocks (128 rows each)

  // layer 1: A(bf16) = dinv .* (x @ W1^T) ; Hp(bf16) = dinv .* relu(dinv.*(Agg A) + b1)
  k_gemm<KIN, 0><<<GB, 256, 0, stream>>>(x, W1, dinv, b1, A);
  k_agg<0><<<NN / 4, 256, 0, stream>>>((const unsigned short*)A, csr, rp, edeg, dinv, b1, Hp);

  // layer 2 (agg commutes with right-linear): A(fp32 g) = dinv .* (Agg Hp) ;
  //          out = relu(g @ W2^T + b2)
  k_agg<1><<<NN / 4, 256, 0, stream>>>(Hp, csr, rp, edeg, dinv, b2, A);
  k_gemm<HID, 1><<<GB, 256, 0, stream>>>((const float*)A, W2, dinv, b2, out);
}

// Round 12
// 265.907 us; speedup vs baseline: 3.0967x; 1.2799x over previous
//
#include <hip/hip_runtime.h>

static constexpr int NN  = 100000;   // nodes
static constexpr int NE  = 1200000;  // edges
static constexpr int KIN = 256;      // input dim
static constexpr int HID = 64;       // hidden == output dim

typedef __attribute__((ext_vector_type(8))) __bf16 bf16v8;
typedef __attribute__((ext_vector_type(4))) float f32x4;

// ---------- bf16 helpers for the agg path (exact widen; RNE narrow)
__device__ __forceinline__ float bf2f(unsigned short u) {
  return __uint_as_float(((unsigned int)u) << 16);
}
__device__ __forceinline__ unsigned short f2bf(float f) {
  unsigned int b = __float_as_uint(f);
  return (unsigned short)((b + 0x7FFFu + ((b >> 16) & 1u)) >> 16);
}

// ---------- zero helper (avoid hipMemsetAsync during graph capture)
__global__ void k_zero(int* __restrict__ p, int n) {
  int i = blockIdx.x * 256 + threadIdx.x;
  if (i < n) p[i] = 0;
}

// ---------- W fp32 -> bf16 hi/lo tables (hi = RNE(bf16), lo = RNE(x - hi))
__global__ void k_wconv(const float* __restrict__ Wsrc, __bf16* __restrict__ Whi,
                        __bf16* __restrict__ Wlo, int n) {
  int i = blockIdx.x * 256 + threadIdx.x;
  if (i < n) {
    float v = Wsrc[i];
    __bf16 h = (__bf16)v;
    Whi[i] = h;
    Wlo[i] = (__bf16)(v - (float)h);
  }
}

// ---------- degree histogram (in-degree from edges only; +1 self-loop in dinv)
__global__ void k_deg(const int* __restrict__ ed, int* __restrict__ edeg) {
  int e = blockIdx.x * 256 + threadIdx.x;
  if (e < NE) atomicAdd(&edeg[ed[NE + e]], 1);
}

__global__ void k_dinv(const int* __restrict__ edeg, float* __restrict__ dinv) {
  int i = blockIdx.x * 256 + threadIdx.x;
  if (i < NN) dinv[i] = rsqrtf((float)(edeg[i] + 1));
}

// ---------- exclusive scan of edeg -> row_ptr (1024 elems/block -> nb = 98 blocks)
__global__ void k_scan1(const int* __restrict__ deg, int* __restrict__ rp, int* __restrict__ bsum) {
  __shared__ int sh[256];
  int t = threadIdx.x;
  int base = blockIdx.x * 1024 + t * 4;
  int v0 = 0, v1 = 0, v2 = 0, v3 = 0;
  if (base + 0 < NN) v0 = deg[base + 0];
  if (base + 1 < NN) v1 = deg[base + 1];
  if (base + 2 < NN) v2 = deg[base + 2];
  if (base + 3 < NN) v3 = deg[base + 3];
  int s = v0 + v1 + v2 + v3;
  sh[t] = s;
  __syncthreads();
  #pragma unroll
  for (int off = 1; off < 256; off <<= 1) {
    int x = (t >= off) ? sh[t - off] : 0;
    __syncthreads();
    sh[t] += x;
    __syncthreads();
  }
  int pre = sh[t] - s;
  if (t == 255) bsum[blockIdx.x] = sh[255];
  if (base + 0 < NN) rp[base + 0] = pre;
  pre += v0;
  if (base + 1 < NN) rp[base + 1] = pre;
  pre += v1;
  if (base + 2 < NN) rp[base + 2] = pre;
  pre += v2;
  if (base + 3 < NN) rp[base + 3] = pre;
}

// parallel 128-lane scan of block sums (nb <= 128)
__global__ void k_scan2(int* __restrict__ bsum, int nb) {
  __shared__ int sh[128];
  int t = threadIdx.x;
  int v = (t < nb) ? bsum[t] : 0;
  sh[t] = v;
  __syncthreads();
  #pragma unroll
  for (int off = 1; off < 128; off <<= 1) {
    int x = (t >= off) ? sh[t - off] : 0;
    __syncthreads();
    sh[t] += x;
    __syncthreads();
  }
  if (t < nb) bsum[t] = sh[t] - v;  // exclusive
}

__global__ void k_scan3(int* __restrict__ rp, const int* __restrict__ bsum, int* __restrict__ cur) {
  int i = blockIdx.x * 256 + threadIdx.x;
  if (i < NN) {
    int v = rp[i] + bsum[i >> 10];
    rp[i] = v;
    cur[i] = v;
  }
}

__global__ void k_scatter(const int* __restrict__ ed, int* __restrict__ cur, int* __restrict__ csr) {
  int e = blockIdx.x * 256 + threadIdx.x;
  if (e < NE) {
    int src = ed[e];
    int dst = ed[NE + e];
    int pos = atomicAdd(&cur[dst], 1);
    csr[pos] = src;
  }
}

// ---------- MFMA GEMM: Y[r][c] = sum_k X[r][k] * W[c][k]  (torch W = [out][in] = B^T)
// bf16 hi/lo split of both operands -> 3 MFMA terms (hi*hi + lo*hi + hi*lo), ~fp32 accurate.
// Block = 64 rows x 4 waves; wave = 16-col slab x 4 row-tiles of 16x16x32 MFMA.
// LDS: X hi/lo [64][40]bf16 (80B row stride: 16B-aligned b128 frags, 2-way conflict = free),
//      W hi/lo [64][40]bf16 from pre-converted global tables (L2-resident).
// Frag map (m89/m91 convention): a[b]=X[rt*16+(l&15)][kt*32+(l>>4)*8+b],
//                                b[b]=W[wc+(l&15)][kt*32+(l>>4)*8+b],
//                                C: col=lane&15, row=(lane>>4)*4+reg.
// Epilogue transposes acc through LDS (overlaid) for coalesced stores.
// MODE 0: Y(bf16) = dinv[r]*acc; MODE 1: Y(fp32) = relu(acc + bias).
template<int K, int MODE>
__global__ void __launch_bounds__(256, 4)
k_gemm(const float* __restrict__ X, const __bf16* __restrict__ Whi, const __bf16* __restrict__ Wlo,
       const float* __restrict__ dinv, const float* __restrict__ bias, void* __restrict__ Yv) {
  constexpr int KT = 32;
  constexpr int NT = K / KT;
  constexpr int LS = 40;                 // bf16 row stride (80 B)
  constexpr int CS = 68;                 // epilogue f32 row stride
  __shared__ __align__(16) char smem[4 * 64 * LS * 2];  // 20480 B; cl overlay needs 17408
  __bf16* xh = (__bf16*)smem;
  __bf16* xl = xh + 64 * LS;
  __bf16* wh = xl + 64 * LS;
  __bf16* wl = wh + 64 * LS;
  float*  cl = (float*)smem;             // [64][CS] epilogue overlay

  const int t = threadIdx.x;
  const int l = t & 63;
  const int wc = (t >> 6) * 16;          // wave's column base
  const int rowbase = blockIdx.x * 64;

  f32x4 acc[4];
  #pragma unroll
  for (int rt = 0; rt < 4; ++rt) acc[rt] = (f32x4){0.f, 0.f, 0.f, 0.f};

  const int sr = t >> 2;                 // staging row/col (0..63)
  const int kc = (t & 3) * 8;            // staging k-chunk (0,8,16,24)

  for (int kt = 0; kt < NT; ++kt) {
    __syncthreads();                     // previous tile fully consumed
    {
      // stage X row sr, 8 elements: fp32 -> hi/lo bf16
      int gr = rowbase + sr;
      float4 v0 = make_float4(0.f, 0.f, 0.f, 0.f), v1 = v0;
      if (gr < NN) {
        const float* xp = X + (size_t)gr * K + kt * KT + kc;
        v0 = *reinterpret_cast<const float4*>(xp);
        v1 = *reinterpret_cast<const float4*>(xp + 4);
      }
      float e[8] = {v0.x, v0.y, v0.z, v0.w, v1.x, v1.y, v1.z, v1.w};
      bf16v8 hv, lv;
      #pragma unroll
      for (int j = 0; j < 8; ++j) {
        __bf16 h = (__bf16)e[j];
        hv[j] = h;
        lv[j] = (__bf16)(e[j] - (float)h);
      }
      *reinterpret_cast<bf16v8*>(&xh[sr * LS + kc]) = hv;
      *reinterpret_cast<bf16v8*>(&xl[sr * LS + kc]) = lv;
      // stage W col sr from pre-converted bf16 tables (16 B loads)
      *reinterpret_cast<bf16v8*>(&wh[sr * LS + kc]) =
          *reinterpret_cast<const bf16v8*>(Whi + (size_t)sr * K + kt * KT + kc);
      *reinterpret_cast<bf16v8*>(&wl[sr * LS + kc]) =
          *reinterpret_cast<const bf16v8*>(Wlo + (size_t)sr * K + kt * KT + kc);
    }
    __syncthreads();

    const int bo = (wc + (l & 15)) * LS + (l >> 4) * 8;
    bf16v8 bh = *reinterpret_cast<const bf16v8*>(&wh[bo]);
    bf16v8 bl = *reinterpret_cast<const bf16v8*>(&wl[bo]);
    #pragma unroll
    for (int rt = 0; rt < 4; ++rt) {
      const int ao = (rt * 16 + (l & 15)) * LS + (l >> 4) * 8;
      bf16v8 ah = *reinterpret_cast<const bf16v8*>(&xh[ao]);
      bf16v8 al = *reinterpret_cast<const bf16v8*>(&xl[ao]);
      acc[rt] = __builtin_amdgcn_mfma_f32_16x16x32_bf16(ah, bh, acc[rt], 0, 0, 0);
      acc[rt] = __builtin_amdgcn_mfma_f32_16x16x32_bf16(al, bh, acc[rt], 0, 0, 0);
      acc[rt] = __builtin_amdgcn_mfma_f32_16x16x32_bf16(ah, bl, acc[rt], 0, 0, 0);
    }
  }

  // epilogue: transpose through LDS for coalesced output
  __syncthreads();
  #pragma unroll
  for (int rt = 0; rt < 4; ++rt)
    #pragma unroll
    for (int j = 0; j < 4; ++j)
      cl[(rt * 16 + (l >> 4) * 4 + j) * CS + wc + (l & 15)] = acc[rt][j];
  __syncthreads();

  const int r = t >> 2, cc = (t & 3) * 16;
  const int grow = rowbase + r;
  if (grow < NN) {
    if (MODE == 0) {
      float dv = dinv[grow];
      bf16v8 o0, o1;
      #pragma unroll
      for (int j = 0; j < 8; ++j) o0[j] = (__bf16)(cl[r * CS + cc + j] * dv);
      #pragma unroll
      for (int j = 0; j < 8; ++j) o1[j] = (__bf16)(cl[r * CS + cc + 8 + j] * dv);
      __bf16* yp = (__bf16*)Yv + (size_t)grow * HID + cc;
      *reinterpret_cast<bf16v8*>(yp) = o0;
      *reinterpret_cast<bf16v8*>(yp + 8) = o1;
    } else {
      float* yp = (float*)Yv + (size_t)grow * HID + cc;
      #pragma unroll
      for (int c4 = 0; c4 < 4; ++c4) {
        float4 o;
        o.x = fmaxf(cl[r * CS + cc + c4 * 4 + 0] + bias[cc + c4 * 4 + 0], 0.f);
        o.y = fmaxf(cl[r * CS + cc + c4 * 4 + 1] + bias[cc + c4 * 4 + 1], 0.f);
        o.z = fmaxf(cl[r * CS + cc + c4 * 4 + 2] + bias[cc + c4 * 4 + 2], 0.f);
        o.w = fmaxf(cl[r * CS + cc + c4 * 4 + 3] + bias[cc + c4 * 4 + 3], 0.f);
        *reinterpret_cast<float4*>(yp + c4 * 4) = o;
      }
    }
  }
}

// ---------- aggregation over pre-scaled bf16 rows T' (= dinv.*T). One wave per node,
// lane = feature. Fixed 16-wide predicated gather (16 loads in flight). fp32 accumulate.
// MODE 0 (layer1): O(bf16) = dinv[node] * relu(dinv[node]*sum + bias[lane])   (h')
// MODE 1 (layer2): O(fp32) = dinv[node] * sum                                 (g)
template<int MODE>
__global__ void __launch_bounds__(256, 8)
k_agg(const unsigned short* __restrict__ T, const int* __restrict__ csr,
      const int* __restrict__ rp, const int* __restrict__ edeg,
      const float* __restrict__ dinv, const float* __restrict__ bias,
      void* __restrict__ Ov) {
  int node = blockIdx.x * 4 + (threadIdx.x >> 6);
  int lane = threadIdx.x & 63;
  float acc = bf2f(T[(size_t)node * HID + lane]);   // self-loop term (pre-scaled)
  int start = rp[node];
  int len = edeg[node];
  for (int base = 0; base < len; base += 64) {
    int m = min(64, len - base);
    int idx = (lane < m) ? csr[start + base + lane] : 0;   // coalesced index load
    for (int c0 = 0; c0 < m; c0 += 16) {
      float part = 0.f;
      #pragma unroll
      for (int i = 0; i < 16; ++i) {
        int e = c0 + i;
        int s = __shfl(idx, e & 63);
        float v = bf2f(T[(size_t)s * HID + lane]);   // always issued; 16 in flight
        part += (e < m) ? v : 0.f;
      }
      acc += part;
    }
  }
  float dv = dinv[node];
  if (MODE == 0) {
    float h = dv * fmaxf(fmaf(dv, acc, bias[lane]), 0.f);
    ((unsigned short*)Ov)[(size_t)node * HID + lane] = f2bf(h);
  } else {
    ((float*)Ov)[(size_t)node * HID + lane] = dv * acc;
  }
}

extern "C" void kernel_launch(void* const* d_in, const int* in_sizes, int n_in,
                              void* d_out, int out_size, void* d_ws, size_t ws_size,
                              hipStream_t stream) {
  const float* x  = (const float*)d_in[0];
  const int*   ed = (const int*)d_in[1];   // int32 per harness contract
  const float* W1 = (const float*)d_in[2];
  const float* b1 = (const float*)d_in[3];
  const float* W2 = (const float*)d_in[4];
  const float* b2 = (const float*)d_in[5];
  float* out = (float*)d_out;

  char* ws = (char*)d_ws;
  size_t off = 0;
  auto alloc = [&](size_t bytes) {
    char* p = ws + off;
    off = (off + bytes + 255) & ~(size_t)255;
    return p;
  };
  int*    edeg = (int*)alloc((size_t)NN * 4);
  float*  dinv = (float*)alloc((size_t)NN * 4);
  int*    rp   = (int*)alloc((size_t)NN * 4);
  int*    cur  = (int*)alloc((size_t)NN * 4);
  int*    bsum = (int*)alloc(4096);
  int*    csr  = (int*)alloc((size_t)NE * 4);
  // A: first bf16 t1' table (12.8 MB), later fp32 g (25.6 MB)
  float*  A    = (float*)alloc((size_t)NN * HID * 4);
  __bf16* Whi1 = (__bf16*)alloc((size_t)HID * KIN * 2);
  __bf16* Wlo1 = (__bf16*)alloc((size_t)HID * KIN * 2);
  __bf16* Whi2 = (__bf16*)alloc((size_t)HID * HID * 2);
  __bf16* Wlo2 = (__bf16*)alloc((size_t)HID * HID * 2);
  // h' (bf16, 12.8 MB) lives in d_out's first half; final GEMM overwrites all of d_out.
  unsigned short* Hp = (unsigned short*)d_out;

  // ---- CSR build + W conversion
  k_zero<<<(NN + 255) / 256, 256, 0, stream>>>(edeg, NN);
  k_deg<<<(NE + 255) / 256, 256, 0, stream>>>(ed, edeg);
  k_dinv<<<(NN + 255) / 256, 256, 0, stream>>>(edeg, dinv);
  int nb = (NN + 1023) / 1024;   // 98
  k_scan1<<<nb, 256, 0, stream>>>(edeg, rp, bsum);
  k_scan2<<<1, 128, 0, stream>>>(bsum, nb);
  k_scan3<<<(NN + 255) / 256, 256, 0, stream>>>(rp, bsum, cur);
  k_scatter<<<(NE + 255) / 256, 256, 0, stream>>>(ed, cur, csr);
  k_wconv<<<(HID * KIN + 255) / 256, 256, 0, stream>>>(W1, Whi1, Wlo1, HID * KIN);
  k_wconv<<<(HID * HID + 255) / 256, 256, 0, stream>>>(W2, Whi2, Wlo2, HID * HID);

  const int GB = (NN + 63) / 64;  // 1563 gemm blocks (64 rows each)

  // layer 1: A(bf16) = dinv .* (x @ W1^T) ; Hp(bf16) = dinv .* relu(dinv.*(Agg A) + b1)
  k_gemm<KIN, 0><<<GB, 256, 0, stream>>>(x, Whi1, Wlo1, dinv, b1, A);
  k_agg<0><<<NN / 4, 256, 0, stream>>>((const unsigned short*)A, csr, rp, edeg, dinv, b1, Hp);

  // layer 2 (agg commutes with right-linear): A(fp32 g) = dinv .* (Agg Hp) ;
  //          out = relu(g @ W2^T + b2)
  k_agg<1><<<NN / 4, 256, 0, stream>>>(Hp, csr, rp, edeg, dinv, b2, A);
  k_gemm<HID, 1><<<GB, 256, 0, stream>>>((const float*)A, Whi2, Wlo2, dinv, b2, out);
}